// Round 2
// baseline (1910.619 us; speedup 1.0000x reference)
//
#include <hip/hip_runtime.h>
#include <stdint.h>

#define NE    33554432   // 16384*32*64  elements of each (B,W,64) tensor
#define MROWS 524288     // B*W rows of the cat matrix
#define NU    (NE/4)     // packed uints per int8 code tensor (P4 layout)

typedef __attribute__((ext_vector_type(8))) short short8;
typedef __attribute__((ext_vector_type(4))) float f32x4;
typedef unsigned short ushort_t;
typedef unsigned int uint_t;

// ---------- helpers ----------
__device__ __forceinline__ unsigned fenc(float f){
  unsigned u=__float_as_uint(f); return (u&0x80000000u)?~u:(u|0x80000000u);
}
__device__ __forceinline__ float fdec(unsigned u){
  return __uint_as_float((u&0x80000000u)?(u&0x7fffffffu):~u);
}
__device__ __forceinline__ void obs(float mn,float mx,float&s,float&zp){
  mn=fminf(mn,0.f); mx=fmaxf(mx,0.f);
  s=fmaxf((mx-mn)/255.0f,1e-8f);
  zp=fminf(fmaxf(rintf(-128.0f-mn/s),-128.f),127.f);
}
// plain (used only in tiny scalar kernels)
__device__ __forceinline__ float qof(float x,float s,float zp){
  return fminf(fmaxf(rintf(x/s)+zp,-128.f),127.f);
}
__device__ __forceinline__ float fqv(float x,float s,float zp){
  return (qof(x,s,zp)-zp)*s;
}
// Markstein correctly-rounded division: r must be fl(1/s). 3 VALU ops.
__device__ __forceinline__ float fdiv_rn(float x,float s,float r){
  float q0=x*r;
  return __builtin_fmaf(__builtin_fmaf(-s,q0,x),r,q0);
}
__device__ __forceinline__ float qofr(float x,float s,float r,float zp){
  return fminf(fmaxf(rintf(fdiv_rn(x,s,r))+zp,-128.f),127.f);
}
__device__ __forceinline__ float b2f(uint_t u,int r){
  return (float)(int)(signed char)((u>>(8*r))&0xff);
}
__device__ __forceinline__ void wred(float&mn,float&mx){
  #pragma unroll
  for(int o=32;o;o>>=1){mn=fminf(mn,__shfl_xor(mn,o));mx=fmaxf(mx,__shfl_xor(mx,o));}
}

// U slots: 0,1 x | 2,3 h | 4,5 c | 6..13 gates | 14,15 fc | 16,17 ic | 18,19 cn | 20,21 hn
// S slots: 0-5 sx,zx,sh,zh,sc,zc | 6,7 scat,zcat | 8-15 sW,zW | 16-23 sG1,zG1
//          24-31 sA2,zA2 | 32-35 sfc,zfc,sic,zic | 36,37 scn,zcn | 38,39 sct,zct | 40,41 shn,zhn

__global__ void k0_init(unsigned* U){
  int t=threadIdx.x;
  if(t<11){U[2*t]=0xFFFFFFFFu;U[2*t+1]=0u;}
}

__global__ __launch_bounds__(256) void k1_minmax(const float* __restrict__ x,
    const float* __restrict__ h,const float* __restrict__ c,unsigned* U){
  __shared__ float red[8];
  int t=blockIdx.x*256+threadIdx.x, stride=gridDim.x*256;
  int w=threadIdx.x>>6,l=threadIdx.x&63;
  const float4* ps[3]={(const float4*)x,(const float4*)h,(const float4*)c};
  for(int q=0;q<3;q++){
    float mn=3.4e38f,mx=-3.4e38f;
    const float4* p=ps[q];
    for(int e=t;e<NE/4;e+=stride){
      float4 v=p[e];
      mn=fminf(mn,fminf(fminf(v.x,v.y),fminf(v.z,v.w)));
      mx=fmaxf(mx,fmaxf(fmaxf(v.x,v.y),fmaxf(v.z,v.w)));
    }
    wred(mn,mx);
    if(l==0){red[w]=mn;red[4+w]=mx;}
    __syncthreads();
    if(threadIdx.x==0){
      float bmn=fminf(fminf(red[0],red[1]),fminf(red[2],red[3]));
      float bmx=fmaxf(fmaxf(red[4],red[5]),fmaxf(red[6],red[7]));
      atomicMin(&U[2*q],fenc(bmn)); atomicMax(&U[2*q+1],fenc(bmx));
    }
    __syncthreads();
  }
}

__global__ __launch_bounds__(256) void k2_prep(const float* Wi,const float* bi,
    const float* Wf,const float* bfv,const float* Wo,const float* bo,
    const float* Wcg,const float* bcg,
    const unsigned* U,float* S,ushort_t* Wc,float* bq){
  __shared__ float smn[256],smx[256],sP[4];
  int t=threadIdx.x;
  if(t==0){
    float xmn=fdec(U[0]),xmx=fdec(U[1]),hmn=fdec(U[2]),hmx=fdec(U[3]),cmn=fdec(U[4]),cmx=fdec(U[5]);
    float sx,zx,sh,zh,sc,zc;
    obs(xmn,xmx,sx,zx);obs(hmn,hmx,sh,zh);obs(cmn,cmx,sc,zc);
    S[0]=sx;S[1]=zx;S[2]=sh;S[3]=zh;S[4]=sc;S[5]=zc;
    float cmn2=fminf(fqv(xmn,sx,zx),fqv(hmn,sh,zh));
    float cmx2=fmaxf(fqv(xmx,sx,zx),fqv(hmx,sh,zh));
    float scat,zcat;obs(cmn2,cmx2,scat,zcat);S[6]=scat;S[7]=zcat;
  }
  const float* Wp[4]={Wi,Wf,Wo,Wcg};
  const float* bp[4]={bi,bfv,bo,bcg};
  for(int g=0;g<4;g++){
    float mn=3.4e38f,mx=-3.4e38f;
    for(int i=t;i<8192;i+=256){float v=Wp[g][i];mn=fminf(mn,v);mx=fmaxf(mx,v);}
    smn[t]=mn;smx[t]=mx;__syncthreads();
    for(int ss=128;ss;ss>>=1){
      if(t<ss){smn[t]=fminf(smn[t],smn[t+ss]);smx[t]=fmaxf(smx[t],smx[t+ss]);}
      __syncthreads();
    }
    if(t==0){
      float s_,z_;obs(smn[0],smx[0],s_,z_);
      S[8+2*g]=s_;S[9+2*g]=z_;sP[0]=s_;sP[1]=z_;
      float bmn=3.4e38f,bmx=-3.4e38f;
      for(int i=0;i<64;i++){float v=bp[g][i];bmn=fminf(bmn,v);bmx=fmaxf(bmx,v);}
      float sb,zb;obs(bmn,bmx,sb,zb);sP[2]=sb;sP[3]=zb;
    }
    __syncthreads();
    float s_=sP[0],z_=sP[1],sb=sP[2],zb=sP[3];
    for(int i=t;i<8192;i+=256){
      float cv=qof(Wp[g][i],s_,z_)-z_;     // centered integer, exact in bf16
      Wc[g*8192+i]=(ushort_t)(__float_as_uint(cv)>>16);
    }
    if(t<64) bq[g*64+t]=fqv(bp[g][t],sb,zb);
    __syncthreads();
  }
}

// cat -> centered bf16 (d_out h-half scratch), c -> P4 int8 codes
__global__ __launch_bounds__(256) void k3_quant(const float* __restrict__ x,
    const float* __restrict__ h,const float* __restrict__ c,
    const float* __restrict__ S,ushort_t* __restrict__ catc,uint_t* __restrict__ Qc4){
  float sx=S[0],zx=S[1],sh=S[2],zh=S[3],sc=S[4],zc=S[5],scat=S[6],zcat=S[7];
  float rx=1.0f/sx, rh=1.0f/sh, rc=1.0f/sc, rcat=1.0f/scat;
  int t=blockIdx.x*256+threadIdx.x, stride=gridDim.x*256;
  const float4* xp=(const float4*)x; const float4* hp=(const float4*)h;
  for(int e=t;e<MROWS*32;e+=stride){
    int row=e>>5,k4=e&31;
    float4 v; float s1,z1,r1;
    if(k4<16){v=xp[row*16+k4];s1=sx;z1=zx;r1=rx;}
    else     {v=hp[row*16+(k4-16)];s1=sh;z1=zh;r1=rh;}
    float c0=qofr((qofr(v.x,s1,r1,z1)-z1)*s1,scat,rcat,zcat)-zcat;
    float c1=qofr((qofr(v.y,s1,r1,z1)-z1)*s1,scat,rcat,zcat)-zcat;
    float c2=qofr((qofr(v.z,s1,r1,z1)-z1)*s1,scat,rcat,zcat)-zcat;
    float c3=qofr((qofr(v.w,s1,r1,z1)-z1)*s1,scat,rcat,zcat)-zcat;
    uint2 o;
    o.x=(__float_as_uint(c0)>>16)|((__float_as_uint(c1)>>16)<<16);
    o.y=(__float_as_uint(c2)>>16)|((__float_as_uint(c3)>>16)<<16);
    ((uint2*)catc)[e]=o;
  }
  const float4* cp=(const float4*)c;
  for(int wi=t;wi<NE/16;wi+=stride){
    int rg=wi>>4, cg=wi&15;
    const float4* base=cp + (size_t)rg*64 + cg;    // float4 index (rg*4+r)*16+cg
    float4 a0=base[0],a1=base[16],a2=base[32],a3=base[48];
    #define Q8(v) ((int)qofr((v),sc,rc,zc)&0xff)
    uint_t o0=(uint_t)Q8(a0.x)|((uint_t)Q8(a1.x)<<8)|((uint_t)Q8(a2.x)<<16)|((uint_t)Q8(a3.x)<<24);
    uint_t o1=(uint_t)Q8(a0.y)|((uint_t)Q8(a1.y)<<8)|((uint_t)Q8(a2.y)<<16)|((uint_t)Q8(a3.y)<<24);
    uint_t o2=(uint_t)Q8(a0.z)|((uint_t)Q8(a1.z)<<8)|((uint_t)Q8(a2.z)<<16)|((uint_t)Q8(a3.z)<<24);
    uint_t o3=(uint_t)Q8(a0.w)|((uint_t)Q8(a1.w)<<8)|((uint_t)Q8(a2.w)<<16)|((uint_t)Q8(a3.w)<<24);
    #undef Q8
    uint4 ov; ov.x=o0;ov.y=o1;ov.z=o2;ov.w=o3;
    *(uint4*)(Qc4 + (size_t)rg*64 + cg*4)=ov;
  }
}

// GEMM pass 1: gate pre-activation minmax only
__global__ __launch_bounds__(256,2) void g0_minmax(const ushort_t* __restrict__ catc,
    const ushort_t* __restrict__ Wc,const float* __restrict__ S,
    const float* __restrict__ bq,unsigned* U){
  int tid=threadIdx.x,w=tid>>6,l=tid&63,l15=l&15,lq=l>>4;
  float sgp=S[6]*S[8+2*w];
  short8 bf[4][4];
  #pragma unroll
  for(int nt=0;nt<4;nt++)
    #pragma unroll
    for(int ks=0;ks<4;ks++)
      bf[nt][ks]=*(const short8*)(Wc+w*8192+(nt*16+l15)*128+ks*32+lq*8);
  float bqr[4];
  #pragma unroll
  for(int nt=0;nt<4;nt++) bqr[nt]=bq[w*64+nt*16+l15];
  float mn=3.4e38f,mx=-3.4e38f;
  for(int gi=0;gi<8;gi++){
    int rowbase=(blockIdx.x*8+gi)*64;
    #pragma unroll
    for(int mt=0;mt<4;mt++){
      const ushort_t* arow=catc+(size_t)(rowbase+mt*16+l15)*128;
      short8 af[4];
      #pragma unroll
      for(int ks=0;ks<4;ks++) af[ks]=*(const short8*)(arow+ks*32+lq*8);
      f32x4 acc[4];
      #pragma unroll
      for(int nt=0;nt<4;nt++) acc[nt]=(f32x4){0.f,0.f,0.f,0.f};
      #pragma unroll
      for(int ks=0;ks<4;ks++)
        #pragma unroll
        for(int nt=0;nt<4;nt++)
          acc[nt]=__builtin_amdgcn_mfma_f32_16x16x32_bf16(af[ks],bf[nt][ks],acc[nt],0,0,0);
      #pragma unroll
      for(int nt=0;nt<4;nt++)
        #pragma unroll
        for(int r=0;r<4;r++){
          float v=__builtin_fmaf(sgp,acc[nt][r],bqr[nt]);
          mn=fminf(mn,v);mx=fmaxf(mx,v);
        }
    }
  }
  wred(mn,mx);
  if(l==0){atomicMin(&U[6+2*w],fenc(mn));atomicMax(&U[7+2*w],fenc(mx));}
}

// GEMM pass 2: emit activation codes (P4) for all 4 gates + fc/ic minmax
__global__ __launch_bounds__(256,2) void gemm_codes(const ushort_t* __restrict__ catc,
    const ushort_t* __restrict__ Wc,const float* __restrict__ S,const float* __restrict__ bq,
    const uint_t* __restrict__ Qc4,uint_t* __restrict__ Qi,uint_t* __restrict__ Qf,
    uint_t* __restrict__ Qo,uint_t* __restrict__ Qcg,unsigned* U){
  __shared__ uint_t packT[4][16][80];   // stride 80 uints: rg bank offset = 16 -> conflict-free
  int tid=threadIdx.x,w=tid>>6,l=tid&63,l15=l&15,lq=l>>4;
  float sgp=S[6]*S[8+2*w];
  float sg1=S[16+2*w],zg1=S[17+2*w],rg1=1.0f/sg1;
  float sa2=S[24+2*w],za2=S[25+2*w],ra2=1.0f/sa2;
  float r6=1.0f/6.0f;
  // part2 scalars
  float sa_i=S[24],za_i=S[25],sa_f=S[26],za_f=S[27],sa_g=S[30],za_g=S[31];
  float sc=S[4],zc=S[5];
  short8 bf[4][4];
  #pragma unroll
  for(int nt=0;nt<4;nt++)
    #pragma unroll
    for(int ks=0;ks<4;ks++)
      bf[nt][ks]=*(const short8*)(Wc+w*8192+(nt*16+l15)*128+ks*32+lq*8);
  float bqr[4];
  #pragma unroll
  for(int nt=0;nt<4;nt++) bqr[nt]=bq[w*64+nt*16+l15];
  float fcmn=3.4e38f,fcmx=-3.4e38f,icmn=3.4e38f,icmx=-3.4e38f;
  for(int gi=0;gi<8;gi++){
    int grp=blockIdx.x*8+gi;
    int rowbase=grp*64;
    #pragma unroll
    for(int mt=0;mt<4;mt++){
      const ushort_t* arow=catc+(size_t)(rowbase+mt*16+l15)*128;
      short8 af[4];
      #pragma unroll
      for(int ks=0;ks<4;ks++) af[ks]=*(const short8*)(arow+ks*32+lq*8);
      f32x4 acc[4];
      #pragma unroll
      for(int nt=0;nt<4;nt++) acc[nt]=(f32x4){0.f,0.f,0.f,0.f};
      #pragma unroll
      for(int ks=0;ks<4;ks++)
        #pragma unroll
        for(int nt=0;nt<4;nt++)
          acc[nt]=__builtin_amdgcn_mfma_f32_16x16x32_bf16(af[ks],bf[nt][ks],acc[nt],0,0,0);
      #pragma unroll
      for(int nt=0;nt<4;nt++){
        uint_t pk=0;
        #pragma unroll
        for(int r=0;r<4;r++){
          float v=__builtin_fmaf(sgp,acc[nt][r],bqr[nt]);
          float q1=fminf(fmaxf(rintf(fdiv_rn(v,sg1,rg1))+zg1,-128.f),127.f);
          float g1=(q1-zg1)*sg1;
          float a=(w==3)?fminf(fmaxf(g1,-1.f),1.f)
                        :fminf(fmaxf(fdiv_rn(g1,6.0f,r6)+0.5f,0.f),1.f);
          float q2=fminf(fmaxf(rintf(fdiv_rn(a,sa2,ra2))+za2,-128.f),127.f);
          pk|=((uint_t)((int)q2&0xff))<<(8*r);
        }
        packT[w][mt*4+lq][nt*16+l15]=pk;
      }
    }
    __syncthreads();
    // coalesced global write of the group's codes (g == it, wave-uniform)
    #pragma unroll
    for(int it=0;it<4;it++){
      int j4=tid+256*it;
      int g=j4>>8, o=(j4&255)*4;
      uint_t* qp=(g==0)?Qi:(g==1)?Qf:(g==2)?Qo:Qcg;
      uint4 v=*(const uint4*)&packT[g][o>>6][o&63];
      *(uint4*)(qp+(size_t)grp*1024+o)=v;
    }
    // fc/ic minmax (exact reference fp32 op order)
    #pragma unroll
    for(int it=0;it<4;it++){
      int j2=tid+256*it;
      int rg=j2>>6,col=j2&63;
      uint_t ui=packT[0][rg][col],uf=packT[1][rg][col],ug=packT[3][rg][col];
      uint_t uc=Qc4[(size_t)grp*1024+j2];
      #pragma unroll
      for(int r=0;r<4;r++){
        float ai=(b2f(ui,r)-za_i)*sa_i;
        float afv=(b2f(uf,r)-za_f)*sa_f;
        float ag=(b2f(ug,r)-za_g)*sa_g;
        float cv=(b2f(uc,r)-zc)*sc;
        float fc=afv*cv, ic=ai*ag;
        fcmn=fminf(fcmn,fc);fcmx=fmaxf(fcmx,fc);
        icmn=fminf(icmn,ic);icmx=fmaxf(icmx,ic);
      }
    }
    __syncthreads();
  }
  wred(fcmn,fcmx);
  if(l==0){atomicMin(&U[14],fenc(fcmn));atomicMax(&U[15],fenc(fcmx));}
  wred(icmn,icmx);
  if(l==0){atomicMin(&U[16],fenc(icmn));atomicMax(&U[17],fenc(icmx));}
}

__global__ void k_post(int stage,const unsigned* U,float* S){
  if(threadIdx.x!=0||blockIdx.x!=0)return;
  if(stage==0){
    for(int g=0;g<4;g++){
      float mn=fdec(U[6+2*g]),mx=fdec(U[7+2*g]);
      float s1,z1;obs(mn,mx,s1,z1);S[16+2*g]=s1;S[17+2*g]=z1;
      float gmn=fqv(mn,s1,z1),gmx=fqv(mx,s1,z1);
      float amn,amx;
      if(g==3){amn=fminf(fmaxf(gmn,-1.f),1.f);amx=fminf(fmaxf(gmx,-1.f),1.f);}
      else{amn=fminf(fmaxf(gmn/6.0f+0.5f,0.f),1.f);amx=fminf(fmaxf(gmx/6.0f+0.5f,0.f),1.f);}
      float s2,z2;obs(amn,amx,s2,z2);S[24+2*g]=s2;S[25+2*g]=z2;
    }
  } else if(stage==1){
    float s,z;
    obs(fdec(U[14]),fdec(U[15]),s,z);S[32]=s;S[33]=z;
    obs(fdec(U[16]),fdec(U[17]),s,z);S[34]=s;S[35]=z;
  } else if(stage==2){
    float mn=fdec(U[18]),mx=fdec(U[19]);
    float s,z;obs(mn,mx,s,z);S[36]=s;S[37]=z;
    float tmn=fminf(fmaxf(fqv(mn,s,z),-1.f),1.f);
    float tmx=fminf(fmaxf(fqv(mx,s,z),-1.f),1.f);
    float s2,z2;obs(tmn,tmx,s2,z2);S[38]=s2;S[39]=z2;
  } else {
    float s,z;obs(fdec(U[20]),fdec(U[21]),s,z);S[40]=s;S[41]=z;
  }
}

// elementwise: c_next raw minmax
__global__ __launch_bounds__(256) void elem2(const uint_t* __restrict__ Qi,
    const uint_t* __restrict__ Qf,const uint_t* __restrict__ Qcg,
    const uint_t* __restrict__ Qc4,const float* __restrict__ S,unsigned* U){
  float sa_i=S[24],za_i=S[25],sa_f=S[26],za_f=S[27],sa_g=S[30],za_g=S[31];
  float sc=S[4],zc=S[5];
  float sfc=S[32],zfc=S[33],rfc=1.0f/sfc;
  float sic=S[34],zic=S[35],ric=1.0f/sic;
  int t=blockIdx.x*256+threadIdx.x,stride=gridDim.x*256,l=threadIdx.x&63;
  float mn=3.4e38f,mx=-3.4e38f;
  for(int u=t;u<NU;u+=stride){
    uint_t ui=Qi[u],uf=Qf[u],ug=Qcg[u],uc=Qc4[u];
    #pragma unroll
    for(int r=0;r<4;r++){
      float ai=(b2f(ui,r)-za_i)*sa_i;
      float afv=(b2f(uf,r)-za_f)*sa_f;
      float ag=(b2f(ug,r)-za_g)*sa_g;
      float cv=(b2f(uc,r)-zc)*sc;
      float fc=afv*cv, ic=ai*ag;
      float fcv=(qofr(fc,sfc,rfc,zfc)-zfc)*sfc;
      float icv=(qofr(ic,sic,ric,zic)-zic)*sic;
      float cn=fcv+icv;
      mn=fminf(mn,cn);mx=fmaxf(mx,cn);
    }
  }
  wred(mn,mx);
  if(l==0){atomicMin(&U[18],fenc(mn));atomicMax(&U[19],fenc(mx));}
}

// elementwise: c_next codes (P4) + h_raw minmax
__global__ __launch_bounds__(256) void elem3(const uint_t* __restrict__ Qi,
    const uint_t* __restrict__ Qf,const uint_t* __restrict__ Qcg,
    const uint_t* __restrict__ Qo,const uint_t* __restrict__ Qc4,
    const float* __restrict__ S,uint_t* __restrict__ Qcn,unsigned* U){
  float sa_i=S[24],za_i=S[25],sa_f=S[26],za_f=S[27],sa_g=S[30],za_g=S[31];
  float so2=S[28],zo2=S[29];
  float sc=S[4],zc=S[5];
  float sfc=S[32],zfc=S[33],rfc=1.0f/sfc;
  float sic=S[34],zic=S[35],ric=1.0f/sic;
  float scn=S[36],zcn=S[37],rcn=1.0f/scn;
  float sct=S[38],zct=S[39],rct=1.0f/sct;
  int t=blockIdx.x*256+threadIdx.x,stride=gridDim.x*256,l=threadIdx.x&63;
  float mn=3.4e38f,mx=-3.4e38f;
  for(int u=t;u<NU;u+=stride){
    uint_t ui=Qi[u],uf=Qf[u],ug=Qcg[u],uo=Qo[u],uc=Qc4[u];
    uint_t pk=0;
    #pragma unroll
    for(int r=0;r<4;r++){
      float ai=(b2f(ui,r)-za_i)*sa_i;
      float afv=(b2f(uf,r)-za_f)*sa_f;
      float ag=(b2f(ug,r)-za_g)*sa_g;
      float cv=(b2f(uc,r)-zc)*sc;
      float fc=afv*cv, ic=ai*ag;
      float fcv=(qofr(fc,sfc,rfc,zfc)-zfc)*sfc;
      float icv=(qofr(ic,sic,ric,zic)-zic)*sic;
      float cn=fcv+icv;
      float qcf=qofr(cn,scn,rcn,zcn);
      float cnv=(qcf-zcn)*scn;
      pk|=((uint_t)((int)qcf&0xff))<<(8*r);
      float ct=fminf(fmaxf(cnv,-1.f),1.f);
      float ctv=(qofr(ct,sct,rct,zct)-zct)*sct;
      float ao=(b2f(uo,r)-zo2)*so2;
      float hr=ao*ctv;
      mn=fminf(mn,hr);mx=fmaxf(mx,hr);
    }
    Qcn[u]=pk;
  }
  wred(mn,mx);
  if(l==0){atomicMin(&U[20],fenc(mn));atomicMax(&U[21],fenc(mx));}
}

// final: h_next + c_next outputs (standard row-major layout)
__global__ __launch_bounds__(256) void k9_hout(const uint_t* __restrict__ Qo,
    const uint_t* __restrict__ Qcn,const float* __restrict__ S,
    float* __restrict__ hout,float* __restrict__ cout_){
  float so2=S[28],zo2=S[29];
  float scn=S[36],zcn=S[37];
  float sct=S[38],zct=S[39],rct=1.0f/sct;
  float shn=S[40],zhn=S[41],rhn=1.0f/shn;
  int t=blockIdx.x*256+threadIdx.x,stride=gridDim.x*256;
  for(int u=t;u<NU;u+=stride){
    uint_t uo=Qo[u],un=Qcn[u];
    int rg=u>>6,col=u&63;
    #pragma unroll
    for(int r=0;r<4;r++){
      float cnv=(b2f(un,r)-zcn)*scn;
      float ct=fminf(fmaxf(cnv,-1.f),1.f);
      float ctv=(qofr(ct,sct,rct,zct)-zct)*sct;
      float ao=(b2f(uo,r)-zo2)*so2;
      float hr=ao*ctv;
      float qh=qofr(hr,shn,rhn,zhn);
      int idx=(rg*4+r)*64+col;
      hout[idx]=(qh-zhn)*shn;
      cout_[idx]=cnv;
    }
  }
}

extern "C" void kernel_launch(void* const* d_in,const int* in_sizes,int n_in,
                              void* d_out,int out_size,void* d_ws,size_t ws_size,
                              hipStream_t stream){
  (void)in_sizes;(void)n_in;(void)out_size;(void)ws_size;
  const float* x  =(const float*)d_in[0];
  const float* h  =(const float*)d_in[1];
  const float* c  =(const float*)d_in[2];
  const float* Wi =(const float*)d_in[3];  const float* bi =(const float*)d_in[4];
  const float* Wf =(const float*)d_in[5];  const float* bfv=(const float*)d_in[6];
  const float* Wo =(const float*)d_in[7];  const float* bo =(const float*)d_in[8];
  const float* Wcg=(const float*)d_in[9];  const float* bcg=(const float*)d_in[10];

  char* ws=(char*)d_ws;
  unsigned* U =(unsigned*)ws;
  float* S    =(float*)(ws+128);
  float* bq   =(float*)(ws+512);
  ushort_t* Wc=(ushort_t*)(ws+2048);                       // 64 KB
  uint_t* Qc4 =(uint_t*)(ws+(1<<20));                      // NE bytes
  uint_t* Qo  =(uint_t*)(ws+(1<<20)+(size_t)NE);           // NE bytes
  uint_t* Qcn =(uint_t*)(ws+(1<<20)+2*(size_t)NE);         // NE bytes (total = round-1 proven footprint)

  // d_out: h-half = catc scratch (bf16) until k9 writes h; c-half hosts Qi/Qf/Qcg until k9 writes c
  ushort_t* catc=(ushort_t*)d_out;
  uint_t* Qi =(uint_t*)((float*)d_out+NE);
  uint_t* Qf =Qi+NU;
  uint_t* Qcg=Qf+NU;
  float* h_out=(float*)d_out;
  float* c_out=(float*)d_out+NE;

  k0_init<<<1,64,0,stream>>>(U);
  k1_minmax<<<2048,256,0,stream>>>(x,h,c,U);
  k2_prep<<<1,256,0,stream>>>(Wi,bi,Wf,bfv,Wo,bo,Wcg,bcg,U,S,Wc,bq);
  k3_quant<<<2048,256,0,stream>>>(x,h,c,S,catc,Qc4);
  g0_minmax<<<1024,256,0,stream>>>(catc,Wc,S,bq,U);
  k_post<<<1,64,0,stream>>>(0,U,S);
  gemm_codes<<<1024,256,0,stream>>>(catc,Wc,S,bq,Qc4,Qi,Qf,Qo,Qcg,U);
  k_post<<<1,64,0,stream>>>(1,U,S);
  elem2<<<4096,256,0,stream>>>(Qi,Qf,Qcg,Qc4,S,U);
  k_post<<<1,64,0,stream>>>(2,U,S);
  elem3<<<4096,256,0,stream>>>(Qi,Qf,Qcg,Qo,Qc4,S,Qcn,U);
  k_post<<<1,64,0,stream>>>(3,U,S);
  k9_hout<<<4096,256,0,stream>>>(Qo,Qcn,S,h_out,c_out);
}